// Round 1
// baseline (405.398 us; speedup 1.0000x reference)
//
#include <hip/hip_runtime.h>

typedef __attribute__((ext_vector_type(8))) short s8v;     // 8 x bf16 bits
typedef __attribute__((ext_vector_type(4))) float f4v;     // 4 x f32

#define MFMA16(a, b, c) __builtin_amdgcn_mfma_f32_16x16x32_bf16(a, b, c, 0, 0, 0)

__device__ __forceinline__ unsigned short f2bf(float f) {
    union { float f; unsigned int u; } v; v.f = f;
    unsigned int u = v.u;
    unsigned int r = (u + 0x7FFFu + ((u >> 16) & 1u)) >> 16;  // RNE
    return (unsigned short)r;
}

// ---------------------------------------------------------------------------
// Kernel 1: weight convert + transpose.  W[k][n] fp32  ->  Wt[n][k] bf16
// ---------------------------------------------------------------------------
__global__ __launch_bounds__(256) void transpose_cvt_k(
        const float* __restrict__ W0, const float* __restrict__ W1,
        const float* __restrict__ W2, const float* __restrict__ W3,
        unsigned short* __restrict__ T0, unsigned short* __restrict__ T1,
        unsigned short* __restrict__ T2, unsigned short* __restrict__ T3) {
    __shared__ float tile[32][33];
    const float* W; unsigned short* T;
    switch (blockIdx.z) {
        case 0:  W = W0; T = T0; break;
        case 1:  W = W1; T = T1; break;
        case 2:  W = W2; T = T2; break;
        default: W = W3; T = T3; break;
    }
    int tx = threadIdx.x & 31, ty = threadIdx.x >> 5;      // ty: 0..7
    int k0 = blockIdx.x * 32, n0 = blockIdx.y * 32;
#pragma unroll
    for (int i = 0; i < 32; i += 8)
        tile[ty + i][tx] = W[(size_t)(k0 + ty + i) * 1024 + n0 + tx];
    __syncthreads();
#pragma unroll
    for (int i = 0; i < 32; i += 8)
        T[(size_t)(n0 + ty + i) * 1024 + k0 + tx] = f2bf(tile[tx][ty + i]);
}

// ---------------------------------------------------------------------------
// Kernel 2: GEMM  C[8192][1024] = A[8192][1024] @ Bt[1024][1024]^T + bias
//   A: fp32 (converted on stage) or bf16.  Out: bf16 (ws) or fp32 (d_out).
//   128x128 block tile, BK=32, 4 waves (each 64x64), 16x16x32 bf16 MFMA.
// ---------------------------------------------------------------------------
template <typename AT, bool OUT_F32>
__global__ __launch_bounds__(256, 2) void gemm_bt_k(
        const AT* __restrict__ A, const unsigned short* __restrict__ Bt,
        const float* __restrict__ bias, void* __restrict__ C) {
    constexpr int Kd = 1024, Nd = 1024;
    constexpr int LDT = 40;                         // 32 + 8 pad (bf16 elems)
    __shared__ __attribute__((aligned(16))) unsigned short As[128 * LDT];
    __shared__ __attribute__((aligned(16))) unsigned short Bs[128 * LDT];

    const int tid  = threadIdx.x;
    const int lane = tid & 63, wave = tid >> 6;
    const int g = lane >> 4, li = lane & 15;
    const int wr = wave >> 1, wc = wave & 1;
    const int row0 = blockIdx.y * 128, col0 = blockIdx.x * 128;

    f4v acc[4][4];
#pragma unroll
    for (int m = 0; m < 4; m++)
#pragma unroll
        for (int n = 0; n < 4; n++) acc[m][n] = (f4v){0.f, 0.f, 0.f, 0.f};

    for (int kt = 0; kt < Kd; kt += 32) {
        __syncthreads();
#pragma unroll
        for (int i = 0; i < 2; i++) {
            int e = (i * 256 + tid) * 8;
            int r = e >> 5, kk = e & 31;
            s8v a8;
            if constexpr (sizeof(AT) == 4) {
                const float* ap = (const float*)A + (size_t)(row0 + r) * Kd + kt + kk;
                float4 x = *reinterpret_cast<const float4*>(ap);
                float4 y = *reinterpret_cast<const float4*>(ap + 4);
                a8[0] = (short)f2bf(x.x); a8[1] = (short)f2bf(x.y);
                a8[2] = (short)f2bf(x.z); a8[3] = (short)f2bf(x.w);
                a8[4] = (short)f2bf(y.x); a8[5] = (short)f2bf(y.y);
                a8[6] = (short)f2bf(y.z); a8[7] = (short)f2bf(y.w);
            } else {
                a8 = *reinterpret_cast<const s8v*>(
                        (const unsigned short*)A + (size_t)(row0 + r) * Kd + kt + kk);
            }
            *reinterpret_cast<s8v*>(&As[r * LDT + kk]) = a8;
            s8v b8 = *reinterpret_cast<const s8v*>(Bt + (size_t)(col0 + r) * Kd + kt + kk);
            *reinterpret_cast<s8v*>(&Bs[r * LDT + kk]) = b8;
        }
        __syncthreads();

        s8v af[4], bf[4];
#pragma unroll
        for (int m = 0; m < 4; m++)
            af[m] = *reinterpret_cast<const s8v*>(&As[(wr * 64 + m * 16 + li) * LDT + g * 8]);
#pragma unroll
        for (int n = 0; n < 4; n++)
            bf[n] = *reinterpret_cast<const s8v*>(&Bs[(wc * 64 + n * 16 + li) * LDT + g * 8]);
#pragma unroll
        for (int m = 0; m < 4; m++)
#pragma unroll
            for (int n = 0; n < 4; n++)
                acc[m][n] = MFMA16(af[m], bf[n], acc[m][n]);
    }

#pragma unroll
    for (int n = 0; n < 4; n++) {
        int col = col0 + wc * 64 + n * 16 + li;
        float bv = bias[col];
#pragma unroll
        for (int m = 0; m < 4; m++) {
            int rbase = row0 + wr * 64 + m * 16 + g * 4;
#pragma unroll
            for (int r = 0; r < 4; r++) {
                float v = acc[m][n][r] + bv;
                if constexpr (OUT_F32)
                    ((float*)C)[(size_t)(rbase + r) * Nd + col] = v;
                else
                    ((unsigned short*)C)[(size_t)(rbase + r) * Nd + col] = f2bf(v);
            }
        }
    }
}

// ---------------------------------------------------------------------------
// Kernel 3: flash attention.  Per block: one (b,h) pair, 128 q-rows.
//   4 waves x 32 q-rows.  Q in regs; K row-major LDS; V transposed LDS.
//   Online softmax (running max/sum per row), P via per-wave LDS for PV frags.
// ---------------------------------------------------------------------------
__global__ __launch_bounds__(256, 2) void attn_k(
        const unsigned short* __restrict__ Q, const unsigned short* __restrict__ K,
        const unsigned short* __restrict__ V, unsigned short* __restrict__ Ctx) {
    constexpr int S = 2048, Dm = 1024, DKh = 64;
    constexpr int LDK = 72, LDV = 136, LDP = 136;
    __shared__ __attribute__((aligned(16))) unsigned short K_lds[128 * LDK];   // [s][d]
    __shared__ __attribute__((aligned(16))) unsigned short Vt_lds[64 * LDV];   // [d][s]
    __shared__ __attribute__((aligned(16))) unsigned short P_lds[4][32 * LDP]; // per-wave [q][s]

    const int tid  = threadIdx.x;
    const int lane = tid & 63, wave = tid >> 6;
    const int g = lane >> 4, li = lane & 15;
    const int bh = blockIdx.y, b = bh >> 4, h = bh & 15;
    const int q0 = blockIdx.x * 128 + wave * 32;
    const size_t base = ((size_t)b * S) * Dm + (size_t)h * DKh;

    // Q fragments hoisted to registers
    s8v qf[2][2];
#pragma unroll
    for (int rb = 0; rb < 2; rb++)
#pragma unroll
        for (int ks = 0; ks < 2; ks++)
            qf[rb][ks] = *reinterpret_cast<const s8v*>(
                    Q + base + (size_t)(q0 + rb * 16 + li) * Dm + ks * 32 + g * 8);

    f4v octx[2][4];
    float m_run[2][4], l_run[2][4];
#pragma unroll
    for (int rb = 0; rb < 2; rb++) {
#pragma unroll
        for (int nb = 0; nb < 4; nb++) octx[rb][nb] = (f4v){0.f, 0.f, 0.f, 0.f};
#pragma unroll
        for (int r = 0; r < 4; r++) { m_run[rb][r] = -1e30f; l_run[rb][r] = 0.f; }
    }

    for (int t = 0; t < 16; t++) {
        const int kv0 = t * 128;
        __syncthreads();   // protect prev-tile LDS reads
        // ---- stage K (row-major) and V (transposed) ----
#pragma unroll
        for (int i = 0; i < 4; i++) {
            int e = (i * 256 + tid) * 8;
            int s = e >> 6, d = e & 63;
            s8v k8 = *reinterpret_cast<const s8v*>(K + base + (size_t)(kv0 + s) * Dm + d);
            *reinterpret_cast<s8v*>(&K_lds[s * LDK + d]) = k8;
            s8v v8 = *reinterpret_cast<const s8v*>(V + base + (size_t)(kv0 + s) * Dm + d);
#pragma unroll
            for (int j = 0; j < 8; j++)
                Vt_lds[(d + j) * LDV + s] = (unsigned short)v8[j];
        }
        __syncthreads();

        // ---- scores: S = Q @ K^T ----
        f4v sc[2][8];
#pragma unroll
        for (int rb = 0; rb < 2; rb++)
#pragma unroll
            for (int cb = 0; cb < 8; cb++) sc[rb][cb] = (f4v){0.f, 0.f, 0.f, 0.f};
#pragma unroll
        for (int cb = 0; cb < 8; cb++) {
#pragma unroll
            for (int ks = 0; ks < 2; ks++) {
                s8v kf = *reinterpret_cast<const s8v*>(
                        &K_lds[(cb * 16 + li) * LDK + ks * 32 + g * 8]);
                sc[0][cb] = MFMA16(qf[0][ks], kf, sc[0][cb]);
                sc[1][cb] = MFMA16(qf[1][ks], kf, sc[1][cb]);
            }
        }

        // ---- online softmax ----
#pragma unroll
        for (int rb = 0; rb < 2; rb++) {
            float rmax[4];
#pragma unroll
            for (int r = 0; r < 4; r++) {
                float v = -1e30f;
#pragma unroll
                for (int cb = 0; cb < 8; cb++) v = fmaxf(v, sc[rb][cb][r]);
                rmax[r] = v * 0.125f;
            }
#pragma unroll
            for (int mask = 1; mask < 16; mask <<= 1)
#pragma unroll
                for (int r = 0; r < 4; r++)
                    rmax[r] = fmaxf(rmax[r], __shfl_xor(rmax[r], mask, 64));
#pragma unroll
            for (int r = 0; r < 4; r++) {
                float mn = fmaxf(m_run[rb][r], rmax[r]);
                float scl = __expf(m_run[rb][r] - mn);
                m_run[rb][r] = mn;
                l_run[rb][r] *= scl;
#pragma unroll
                for (int nb = 0; nb < 4; nb++) octx[rb][nb][r] *= scl;
            }
            float rsum[4] = {0.f, 0.f, 0.f, 0.f};
#pragma unroll
            for (int cb = 0; cb < 8; cb++) {
#pragma unroll
                for (int r = 0; r < 4; r++) {
                    float p = __expf(sc[rb][cb][r] * 0.125f - m_run[rb][r]);
                    rsum[r] += p;
                    P_lds[wave][(rb * 16 + g * 4 + r) * LDP + cb * 16 + li] = f2bf(p);
                }
            }
#pragma unroll
            for (int mask = 1; mask < 16; mask <<= 1)
#pragma unroll
                for (int r = 0; r < 4; r++) rsum[r] += __shfl_xor(rsum[r], mask, 64);
#pragma unroll
            for (int r = 0; r < 4; r++) l_run[rb][r] += rsum[r];
        }

        // ---- PV: octx += P @ V ----
#pragma unroll
        for (int ks = 0; ks < 4; ks++) {
            s8v vf[4], pf[2];
#pragma unroll
            for (int nb = 0; nb < 4; nb++)
                vf[nb] = *reinterpret_cast<const s8v*>(
                        &Vt_lds[(nb * 16 + li) * LDV + ks * 32 + g * 8]);
#pragma unroll
            for (int rb = 0; rb < 2; rb++)
                pf[rb] = *reinterpret_cast<const s8v*>(
                        &P_lds[wave][(rb * 16 + li) * LDP + ks * 32 + g * 8]);
#pragma unroll
            for (int rb = 0; rb < 2; rb++)
#pragma unroll
                for (int nb = 0; nb < 4; nb++)
                    octx[rb][nb] = MFMA16(pf[rb], vf[nb], octx[rb][nb]);
        }
    }

    // ---- epilogue: normalize, write bf16 ctx in [b,s,h*64+d] layout ----
#pragma unroll
    for (int rb = 0; rb < 2; rb++)
#pragma unroll
        for (int r = 0; r < 4; r++) {
            float inv = 1.0f / l_run[rb][r];
            int row = q0 + rb * 16 + g * 4 + r;
#pragma unroll
            for (int nb = 0; nb < 4; nb++) {
                int d = nb * 16 + li;
                Ctx[base + (size_t)row * Dm + d] = f2bf(octx[rb][nb][r] * inv);
            }
        }
}

// ---------------------------------------------------------------------------
extern "C" void kernel_launch(void* const* d_in, const int* in_sizes, int n_in,
                              void* d_out, int out_size, void* d_ws, size_t ws_size,
                              hipStream_t stream) {
    const float* query = (const float*)d_in[0];
    const float* key   = (const float*)d_in[1];
    const float* value = (const float*)d_in[2];
    const float* Wq = (const float*)d_in[3];
    const float* bq = (const float*)d_in[4];
    const float* Wk = (const float*)d_in[5];
    const float* bk = (const float*)d_in[6];
    const float* Wv = (const float*)d_in[7];
    const float* bv = (const float*)d_in[8];
    const float* Wo = (const float*)d_in[9];
    const float* bo = (const float*)d_in[10];

    unsigned short* ws = (unsigned short*)d_ws;
    const size_t MD = (size_t)8192 * 1024;
    unsigned short* Qb  = ws;
    unsigned short* Kb  = Qb + MD;
    unsigned short* Vb  = Kb + MD;
    unsigned short* Cb  = Vb + MD;
    unsigned short* Wqt = Cb + MD;
    unsigned short* Wkt = Wqt + 1024 * 1024;
    unsigned short* Wvt = Wkt + 1024 * 1024;
    unsigned short* Wot = Wvt + 1024 * 1024;

    transpose_cvt_k<<<dim3(32, 32, 4), 256, 0, stream>>>(Wq, Wk, Wv, Wo, Wqt, Wkt, Wvt, Wot);
    gemm_bt_k<float, false><<<dim3(8, 64), 256, 0, stream>>>(query, Wqt, bq, Qb);
    gemm_bt_k<float, false><<<dim3(8, 64), 256, 0, stream>>>(key,   Wkt, bk, Kb);
    gemm_bt_k<float, false><<<dim3(8, 64), 256, 0, stream>>>(value, Wvt, bv, Vb);
    attn_k<<<dim3(16, 64), 256, 0, stream>>>(Qb, Kb, Vb, Cb);
    gemm_bt_k<unsigned short, true><<<dim3(8, 64), 256, 0, stream>>>(Cb, Wot, bo, (float*)d_out);
}